// Round 1
// baseline (154.823 us; speedup 1.0000x reference)
//
#include <hip/hip_runtime.h>
#include <math.h>

#define NB   32
#define CC   64
#define LL   1024
#define EPS  1e-6f

// Workspace layout (float units):
//   rnA        [0      .. 32768)   inverse norms rgb
//   rnB        [32768  .. 65536)   inverse norms ir
//   row_max    [65536  .. 98304)
//   row_sum    [98304  .. 131072)
//   row_arg    [131072 .. 163840)  (int)
//   col_sum    [163840 .. 196608)
//   col_packed [196608 .. 262144)  (u64: floatbits<<32 | ~row_idx)
//   loss_acc   [262144 .. 262145)
// Total ~1.05 MB.

__global__ __launch_bounds__(256) void norms_kernel(const float* __restrict__ rgb,
                                                    const float* __restrict__ ir,
                                                    float* __restrict__ rnA,
                                                    float* __restrict__ rnB) {
    int p = blockIdx.x * 256 + threadIdx.x;      // 0..32767 = (n,l)
    int n = p >> 10;
    int l = p & (LL - 1);
    const float* a = rgb + (size_t)n * CC * LL + l;
    const float* b = ir  + (size_t)n * CC * LL + l;
    float sa = 0.f, sb = 0.f;
#pragma unroll 8
    for (int c = 0; c < CC; ++c) {
        float va = a[c * LL]; sa = fmaf(va, va, sa);
        float vb = b[c * LL]; sb = fmaf(vb, vb, sb);
    }
    rnA[p] = 1.0f / fmaxf(sqrtf(sa), 1e-12f);
    rnB[p] = 1.0f / fmaxf(sqrtf(sb), 1e-12f);
}

// One block per (batch, 64-row tile): computes rows [i0,i0+64) x all 1024 cols.
// Row stats finalized directly; col stats merged via global atomics.
__global__ __launch_bounds__(256) void fused_kernel(
        const float* __restrict__ rgb, const float* __restrict__ ir,
        const float* __restrict__ rnA, const float* __restrict__ rnB,
        float* __restrict__ row_max, float* __restrict__ row_sum,
        int* __restrict__ row_arg,
        float* __restrict__ col_sum, unsigned long long* __restrict__ col_packed) {
    __shared__ float sA[CC][64];                  // [c][i] 16 KB (pre-scaled by rnA)
    __shared__ float sB[CC][64];                  // [c][j] 16 KB (pre-scaled by rnB)
    __shared__ float red_sum[16][64];             // 4 KB
    __shared__ unsigned long long red_pk[16][64]; // 8 KB

    const int tid = threadIdx.x;
    const int tx  = tid & 15;
    const int ty  = tid >> 4;
    const int tx4 = tx << 2;
    const int ty4 = ty << 2;
    const int b   = blockIdx.x >> 4;
    const int i0  = (blockIdx.x & 15) << 6;

    const float* Ab = rgb + (size_t)b * CC * LL;
    const float* Bb = ir  + (size_t)b * CC * LL;

    // Load A tile once, folding the per-pixel inverse norm.
    {
        float4 rn = *(const float4*)(rnA + b * LL + i0 + tx4);
#pragma unroll
        for (int r = 0; r < 4; ++r) {
            int c = ty + r * 16;
            float4 v = *(const float4*)(Ab + (size_t)c * LL + i0 + tx4);
            float4 w;
            w.x = v.x * rn.x; w.y = v.y * rn.y; w.z = v.z * rn.z; w.w = v.w * rn.w;
            *(float4*)&sA[c][tx4] = w;
        }
    }

    // Per-thread running row stats (rows ty4..ty4+3, over this thread's 64 j's).
    float rmax[4] = {0.f, 0.f, 0.f, 0.f};   // exp values are > 0
    float rsum[4] = {0.f, 0.f, 0.f, 0.f};
    int   rarg[4] = {0, 0, 0, 0};

    for (int jt = 0; jt < 16; ++jt) {
        const int j0 = jt << 6;
        __syncthreads();   // sB safe to overwrite; red_* safe to overwrite
        {
            float4 rn = *(const float4*)(rnB + b * LL + j0 + tx4);
#pragma unroll
            for (int r = 0; r < 4; ++r) {
                int c = ty + r * 16;
                float4 v = *(const float4*)(Bb + (size_t)c * LL + j0 + tx4);
                float4 w;
                w.x = v.x * rn.x; w.y = v.y * rn.y; w.z = v.z * rn.z; w.w = v.w * rn.w;
                *(float4*)&sB[c][tx4] = w;
            }
        }
        __syncthreads();

        float acc[4][4] = {{0.f}};
#pragma unroll 8
        for (int k = 0; k < CC; ++k) {
            const float4 af = *(const float4*)&sA[k][ty4];
            const float4 bf = *(const float4*)&sB[k][tx4];
            const float av[4] = {af.x, af.y, af.z, af.w};
            const float bv[4] = {bf.x, bf.y, bf.z, bf.w};
#pragma unroll
            for (int u = 0; u < 4; ++u)
#pragma unroll
                for (int v = 0; v < 4; ++v)
                    acc[u][v] = fmaf(av[u], bv[v], acc[u][v]);
        }

        float e[4][4];
#pragma unroll
        for (int u = 0; u < 4; ++u)
#pragma unroll
            for (int v = 0; v < 4; ++v)
                e[u][v] = __expf(acc[u][v] * 10.0f);

        // Row stats: j ascending within thread; strict > keeps first index.
#pragma unroll
        for (int u = 0; u < 4; ++u) {
#pragma unroll
            for (int v = 0; v < 4; ++v) {
                int j = j0 + tx4 + v;
                float ev = e[u][v];
                if (ev > rmax[u]) { rmax[u] = ev; rarg[u] = j; }
                rsum[u] += ev;
            }
        }

        // Col stats within thread (rows i0+ty4+u), then LDS reduce + atomics.
#pragma unroll
        for (int v = 0; v < 4; ++v) {
            float cm = e[0][v]; int ci = 0;
            float cs = e[0][v];
#pragma unroll
            for (int u = 1; u < 4; ++u) {
                float ev = e[u][v];
                if (ev > cm) { cm = ev; ci = u; }
                cs += ev;
            }
            red_sum[ty][tx4 + v] = cs;
            unsigned int inv = ~(unsigned int)(i0 + ty4 + ci);
            red_pk[ty][tx4 + v] =
                ((unsigned long long)__float_as_uint(cm) << 32) | (unsigned long long)inv;
        }
        __syncthreads();
        if (tid < 64) {
            float s = 0.f;
            unsigned long long m = 0ull;
#pragma unroll
            for (int t = 0; t < 16; ++t) {
                s += red_sum[t][tid];
                unsigned long long pk = red_pk[t][tid];
                if (pk > m) m = pk;
            }
            atomicAdd(&col_sum[b * LL + j0 + tid], s);
            atomicMax(&col_packed[b * LL + j0 + tid], m);
        }
    }

    // Row reduction across the 16 tx threads per row.
    __syncthreads();
#pragma unroll
    for (int u = 0; u < 4; ++u) {
        red_sum[tx][ty4 + u] = rsum[u];
        red_pk[tx][ty4 + u] =
            ((unsigned long long)__float_as_uint(rmax[u]) << 32) |
            (unsigned long long)(unsigned int)(~(unsigned int)rarg[u]);
    }
    __syncthreads();
    if (tid < 64) {
        float s = 0.f;
        unsigned long long m = 0ull;
#pragma unroll
        for (int t = 0; t < 16; ++t) {
            s += red_sum[t][tid];
            unsigned long long pk = red_pk[t][tid];
            if (pk > m) m = pk;
        }
        int idx = b * LL + i0 + tid;
        row_sum[idx] = s;
        row_max[idx] = __uint_as_float((unsigned int)(m >> 32));
        row_arg[idx] = (int)(~(unsigned int)(m & 0xFFFFFFFFull));
    }
}

__global__ __launch_bounds__(256) void loss_kernel(
        const float* __restrict__ row_max, const float* __restrict__ row_sum,
        const int* __restrict__ row_arg,
        const float* __restrict__ col_sum,
        const unsigned long long* __restrict__ col_packed,
        float* __restrict__ loss_acc) {
    int t = blockIdx.x * 256 + threadIdx.x;   // 16384 threads, 4 terms each
    float acc = 0.f;
#pragma unroll
    for (int it = 0; it < 4; ++it) {
        int p = t + it * 16384;
        if (p < NB * LL) {
            // rgb2ir2rgb over (b, i) = p
            float m2 = row_max[p], s2 = row_sum[p];
            int b = p >> 10;
            int q = (b << 10) + row_arg[p];
            unsigned long long pk = col_packed[q];
            float m1 = __uint_as_float((unsigned int)(pk >> 32));
            float s1 = col_sum[q];
            acc += logf((m2 / (s2 + EPS)) * (m1 / (s1 + EPS)));
        } else {
            // ir2rgb2ir over (b, j) = p - N*L
            int p2 = p - NB * LL;
            unsigned long long pk = col_packed[p2];
            float m1 = __uint_as_float((unsigned int)(pk >> 32));
            float s1 = col_sum[p2];
            int b = p2 >> 10;
            int q = (b << 10) + (int)(~(unsigned int)(pk & 0xFFFFFFFFull));
            float m2 = row_max[q], s2 = row_sum[q];
            acc += logf((m1 / (s1 + EPS)) * (m2 / (s2 + EPS)));
        }
    }
    // wave reduce (64 lanes) then cross-wave via LDS
#pragma unroll
    for (int off = 32; off > 0; off >>= 1) acc += __shfl_down(acc, off, 64);
    __shared__ float wsum[4];
    int lane = threadIdx.x & 63, w = threadIdx.x >> 6;
    if (lane == 0) wsum[w] = acc;
    __syncthreads();
    if (threadIdx.x == 0) {
        atomicAdd(loss_acc, wsum[0] + wsum[1] + wsum[2] + wsum[3]);
    }
}

__global__ void finalize_kernel(const float* __restrict__ loss_acc,
                                float* __restrict__ out) {
    out[0] = -loss_acc[0] / (float)(2 * NB * LL);
}

extern "C" void kernel_launch(void* const* d_in, const int* in_sizes, int n_in,
                              void* d_out, int out_size, void* d_ws, size_t ws_size,
                              hipStream_t stream) {
    const float* rgb = (const float*)d_in[0];
    const float* ir  = (const float*)d_in[1];
    float* ws = (float*)d_ws;

    float* rnA     = ws;
    float* rnB     = ws + 32768;
    float* row_max = ws + 65536;
    float* row_sum = ws + 98304;
    int*   row_arg = (int*)(ws + 131072);
    float* col_sum = ws + 163840;
    unsigned long long* col_packed = (unsigned long long*)(ws + 196608);
    float* loss_acc = ws + 262144;

    // Zero col_sum + col_packed + loss_acc (contiguous region); ws is poisoned 0xAA.
    hipMemsetAsync(ws + 163840, 0, (size_t)(32768 + 65536 + 1) * sizeof(float), stream);

    norms_kernel<<<128, 256, 0, stream>>>(rgb, ir, rnA, rnB);
    fused_kernel<<<NB * 16, 256, 0, stream>>>(rgb, ir, rnA, rnB,
                                              row_max, row_sum, row_arg,
                                              col_sum, col_packed);
    loss_kernel<<<64, 256, 0, stream>>>(row_max, row_sum, row_arg,
                                        col_sum, col_packed, loss_acc);
    finalize_kernel<<<1, 1, 0, stream>>>(loss_acc, (float*)d_out);
}

// Round 2
// 101.718 us; speedup vs baseline: 1.5221x; 1.5221x over previous
//
#include <hip/hip_runtime.h>
#include <math.h>

#define NB 32
#define CC 64
#define LL 1024
#define EPS 1e-6f

typedef __attribute__((ext_vector_type(8))) __bf16 bf16x8;
typedef __attribute__((ext_vector_type(4))) float f32x4;

// ============================================================================
// MAIN PATH (needs ~8.9 MB ws): transpose+norm prepass -> MFMA gemm+stats ->
// loss -> finalize.
// ws byte layout:
//   At      @ 0         (4 MB)  bf16 [32][1024][64]  normalized rgb, transposed
//   Bt      @ 4194304   (4 MB)  bf16 [32][1024][64]  normalized ir, transposed
//   row_sum @ 8388608   (128 KB) f32[32768]
//   col_sum @ 8519680   (128 KB) f32[32768]
//   row_pk  @ 8650752   (128 KB) u32[32768]  (expbits&~1023)|(1023-j)
//   col_pk  @ 8781824   (128 KB) u32[32768]  (expbits&~1023)|(1023-i)
//   loss    @ 8912896   (4 B)
// ============================================================================

// Grid 1024 = input(2) x batch(32) x lchunk(16). Computes per-pixel inverse
// channel norms from the staged tile (no separate norms kernel), scales,
// converts to bf16, writes transposed [l][c] layout (contiguous 128 B rows).
__global__ __launch_bounds__(256) void transpose_norm_kernel(
        const float* __restrict__ rgb, const float* __restrict__ ir,
        __bf16* __restrict__ At, __bf16* __restrict__ Bt) {
    __shared__ float tile[64][65];   // [c][l], pad 65 to break bank conflicts
    __shared__ float red[4][64];
    __shared__ float rn[64];

    const int t   = threadIdx.x;
    const int blk = blockIdx.x;
    const int in  = blk >> 9;
    const int b   = (blk >> 4) & 31;
    const int l0  = (blk & 15) << 6;
    const float* src = in ? ir : rgb;
    __bf16*      dst = in ? Bt : At;

    const int ll = t & 63, cg = t >> 6;
    const float* sp = src + ((size_t)b << 16) + l0 + ll;
#pragma unroll
    for (int u = 0; u < 16; ++u) {
        int c = cg * 16 + u;
        tile[c][ll] = sp[(size_t)c << 10];      // coalesced 256B per wave
    }
    __syncthreads();

    float ssq = 0.f;
#pragma unroll
    for (int u = 0; u < 16; ++u) {
        float v = tile[cg * 16 + u][ll];
        ssq = fmaf(v, v, ssq);
    }
    red[cg][ll] = ssq;
    __syncthreads();
    if (t < 64) {
        float s = red[0][t] + red[1][t] + red[2][t] + red[3][t];
        rn[t] = 1.0f / fmaxf(sqrtf(s), 1e-12f);
    }
    __syncthreads();

    // Write phase: lane group of 4 covers one full 128 B output row.
    const int lw  = t >> 2;   // 0..63 local l
    const int cg2 = t & 3;    // 0..3, 16 c's each
    const float r = rn[lw];
    bf16x8 v0, v1;
#pragma unroll
    for (int u = 0; u < 8; ++u)
        v0[u] = (__bf16)(tile[cg2 * 16 + u][lw] * r);
#pragma unroll
    for (int u = 0; u < 8; ++u)
        v1[u] = (__bf16)(tile[cg2 * 16 + 8 + u][lw] * r);
    size_t base = ((((size_t)b << 10) + l0 + lw) << 6) + cg2 * 16;
    *(bf16x8*)(dst + base)     = v0;
    *(bf16x8*)(dst + base + 8) = v1;
}

// Grid 2048 = batch(32) x itile(8) x jtile(8); 128x128 output tile per block.
// 4 waves; wave w computes rows [32w,32w+32) x all 128 cols via 16x16x32 MFMA.
// Stats: packed-u32 max/argmax ((expbits&~1023)|(1023-idx)) so ties pick the
// smallest index (matches jnp.argmax first-index semantics within a 2^-13
// band). Rows: shuffle-reduce over the 16 col-lanes -> global atomics.
// Cols: shuffle over quads -> LDS atomics -> global atomics.
__global__ __launch_bounds__(256) void gemm_stats_kernel(
        const __bf16* __restrict__ At, const __bf16* __restrict__ Bt,
        float* __restrict__ row_sum, unsigned* __restrict__ row_pk,
        float* __restrict__ col_sum, unsigned* __restrict__ col_pk) {
    __shared__ __bf16 As[128 * 72];   // [row][k], pad 72 -> balanced b128 banks
    __shared__ __bf16 Bs[128 * 72];   // [col][k]
    __shared__ float    colsum_s[128];
    __shared__ unsigned colpk_s[128];

    const int t   = threadIdx.x;
    const int blk = blockIdx.x;
    const int bb  = blk >> 6;
    const int i0  = ((blk >> 3) & 7) << 7;
    const int j0  = (blk & 7) << 7;

    const __bf16* Ag = At + ((((size_t)bb << 10) + i0) << 6);  // contiguous 16 KB
    const __bf16* Bg = Bt + ((((size_t)bb << 10) + j0) << 6);
#pragma unroll
    for (int it = 0; it < 4; ++it) {
        int u = t + it * 256;          // 1024 tasks x 8 bf16
        int row = u >> 3, seg = u & 7;
        *(bf16x8*)&As[row * 72 + seg * 8] = *(const bf16x8*)(Ag + u * 8);
        *(bf16x8*)&Bs[row * 72 + seg * 8] = *(const bf16x8*)(Bg + u * 8);
    }
    if (t < 128) { colsum_s[t] = 0.f; colpk_s[t] = 0u; }
    __syncthreads();

    const int w = t >> 6, lane = t & 63;
    const int m = lane & 15, q = lane >> 4;

    bf16x8 a[2][2];
#pragma unroll
    for (int rt = 0; rt < 2; ++rt)
#pragma unroll
        for (int kb = 0; kb < 2; ++kb)
            a[rt][kb] = *(bf16x8*)&As[(32 * w + 16 * rt + m) * 72 + kb * 32 + q * 8];

    f32x4 acc[2][8];
#pragma unroll
    for (int rt = 0; rt < 2; ++rt)
#pragma unroll
        for (int ct = 0; ct < 8; ++ct)
            acc[rt][ct] = (f32x4){0.f, 0.f, 0.f, 0.f};

#pragma unroll
    for (int ct = 0; ct < 8; ++ct) {
        bf16x8 b0 = *(bf16x8*)&Bs[(16 * ct + m) * 72 + q * 8];
        bf16x8 b1 = *(bf16x8*)&Bs[(16 * ct + m) * 72 + 32 + q * 8];
#pragma unroll
        for (int rt = 0; rt < 2; ++rt) {
            acc[rt][ct] = __builtin_amdgcn_mfma_f32_16x16x32_bf16(a[rt][0], b0, acc[rt][ct], 0, 0, 0);
            acc[rt][ct] = __builtin_amdgcn_mfma_f32_16x16x32_bf16(a[rt][1], b1, acc[rt][ct], 0, 0, 0);
        }
    }

    // ---- epilogue: exp + row/col stats ----
    float    rsum[2][4]; unsigned rpk[2][4];
    float    csum[8];    unsigned cpk[8];
    unsigned iinv[2][4];
#pragma unroll
    for (int rt = 0; rt < 2; ++rt)
#pragma unroll
        for (int r = 0; r < 4; ++r) {
            rsum[rt][r] = 0.f; rpk[rt][r] = 0u;
            iinv[rt][r] = 1023u - (unsigned)(i0 + 32 * w + 16 * rt + 4 * q + r);
        }
#pragma unroll
    for (int ct = 0; ct < 8; ++ct) { csum[ct] = 0.f; cpk[ct] = 0u; }

#pragma unroll
    for (int ct = 0; ct < 8; ++ct) {
        unsigned jinv = 1023u - (unsigned)(j0 + 16 * ct + m);
#pragma unroll
        for (int rt = 0; rt < 2; ++rt)
#pragma unroll
            for (int r = 0; r < 4; ++r) {
                float e = __expf(acc[rt][ct][r] * 10.0f);
                unsigned eb = __float_as_uint(e) & 0xFFFFFC00u;
                rsum[rt][r] += e;
                unsigned prj = eb | jinv;
                if (prj > rpk[rt][r]) rpk[rt][r] = prj;
                csum[ct] += e;
                unsigned pci = eb | iinv[rt][r];
                if (pci > cpk[ct]) cpk[ct] = pci;
            }
    }

    // Row reduce over the 16 col-lanes (xor 1,2,4,8 stays within the group).
#pragma unroll
    for (int s = 1; s < 16; s <<= 1) {
#pragma unroll
        for (int rt = 0; rt < 2; ++rt)
#pragma unroll
            for (int r = 0; r < 4; ++r) {
                rsum[rt][r] += __shfl_xor(rsum[rt][r], s, 64);
                unsigned o = (unsigned)__shfl_xor((int)rpk[rt][r], s, 64);
                if (o > rpk[rt][r]) rpk[rt][r] = o;
            }
    }
    if (m == 0) {
#pragma unroll
        for (int rt = 0; rt < 2; ++rt)
#pragma unroll
            for (int r = 0; r < 4; ++r) {
                int idx = (bb << 10) + i0 + 32 * w + 16 * rt + 4 * q + r;
                atomicAdd(&row_sum[idx], rsum[rt][r]);
                atomicMax(&row_pk[idx],  rpk[rt][r]);
            }
    }

    // Col reduce over quads (xor 16, 32), then LDS combine across waves.
#pragma unroll
    for (int s = 16; s < 64; s <<= 1) {
#pragma unroll
        for (int ct = 0; ct < 8; ++ct) {
            csum[ct] += __shfl_xor(csum[ct], s, 64);
            unsigned o = (unsigned)__shfl_xor((int)cpk[ct], s, 64);
            if (o > cpk[ct]) cpk[ct] = o;
        }
    }
    if (q == 0) {
#pragma unroll
        for (int ct = 0; ct < 8; ++ct) {
            atomicAdd(&colsum_s[16 * ct + m], csum[ct]);
            atomicMax(&colpk_s[16 * ct + m], cpk[ct]);
        }
    }
    __syncthreads();
    if (t < 128) {
        int idx = (bb << 10) + j0 + t;
        atomicAdd(&col_sum[idx], colsum_s[t]);
        atomicMax(&col_pk[idx],  colpk_s[t]);
    }
}

// NOTE reference broadcasting: the trailing /(sum1+EPS) and /(sum2+EPS) are
// indexed by ELEMENT position, not by argmax (round-1 bug, now fixed).
__global__ __launch_bounds__(256) void loss_kernel2(
        const float* __restrict__ row_sum, const unsigned* __restrict__ row_pk,
        const float* __restrict__ col_sum, const unsigned* __restrict__ col_pk,
        float* __restrict__ loss_acc) {
    int t = blockIdx.x * 256 + threadIdx.x;
    float acc = 0.f;
#pragma unroll
    for (int it = 0; it < 4; ++it) {
        int p = t + it * 16384;
        if (p < NB * LL) {
            unsigned pk2 = row_pk[p];
            float m2 = __uint_as_float(pk2 & 0xFFFFFC00u);
            int j = 1023 - (int)(pk2 & 1023u);
            float s2 = row_sum[p];
            float s1 = col_sum[p];                       // position-indexed!
            unsigned pk1 = col_pk[(p & ~1023) + j];
            float m1 = __uint_as_float(pk1 & 0xFFFFFC00u);
            acc += logf((m2 / (s2 + EPS)) * (m1 / (s1 + EPS)));
        } else {
            int p2 = p - NB * LL;
            unsigned pk1 = col_pk[p2];
            float m1 = __uint_as_float(pk1 & 0xFFFFFC00u);
            int i = 1023 - (int)(pk1 & 1023u);
            float s1 = col_sum[p2];
            float s2 = row_sum[p2];                      // position-indexed!
            unsigned pk2 = row_pk[(p2 & ~1023) + i];
            float m2 = __uint_as_float(pk2 & 0xFFFFFC00u);
            acc += logf((m1 / (s1 + EPS)) * (m2 / (s2 + EPS)));
        }
    }
#pragma unroll
    for (int off = 32; off > 0; off >>= 1) acc += __shfl_down(acc, off, 64);
    __shared__ float wsum[4];
    int lane = threadIdx.x & 63, w = threadIdx.x >> 6;
    if (lane == 0) wsum[w] = acc;
    __syncthreads();
    if (threadIdx.x == 0)
        atomicAdd(loss_acc, wsum[0] + wsum[1] + wsum[2] + wsum[3]);
}

__global__ void finalize_kernel(const float* __restrict__ loss_acc,
                                float* __restrict__ out) {
    out[0] = -loss_acc[0] / (float)(2 * NB * LL);
}

// ============================================================================
// FALLBACK PATH (round-1 fp32 kernels, ~1.05 MB ws) — used if ws too small.
// ============================================================================
__global__ __launch_bounds__(256) void norms_kernel_fb(const float* __restrict__ rgb,
                                                       const float* __restrict__ ir,
                                                       float* __restrict__ rnA,
                                                       float* __restrict__ rnB) {
    int p = blockIdx.x * 256 + threadIdx.x;
    int n = p >> 10;
    int l = p & (LL - 1);
    const float* a = rgb + (size_t)n * CC * LL + l;
    const float* b = ir  + (size_t)n * CC * LL + l;
    float sa = 0.f, sb = 0.f;
#pragma unroll 8
    for (int c = 0; c < CC; ++c) {
        float va = a[c * LL]; sa = fmaf(va, va, sa);
        float vb = b[c * LL]; sb = fmaf(vb, vb, sb);
    }
    rnA[p] = 1.0f / fmaxf(sqrtf(sa), 1e-12f);
    rnB[p] = 1.0f / fmaxf(sqrtf(sb), 1e-12f);
}

__global__ __launch_bounds__(256) void fused_kernel_fb(
        const float* __restrict__ rgb, const float* __restrict__ ir,
        const float* __restrict__ rnA, const float* __restrict__ rnB,
        float* __restrict__ row_max, float* __restrict__ row_sum,
        int* __restrict__ row_arg,
        float* __restrict__ col_sum, unsigned long long* __restrict__ col_packed) {
    __shared__ float sA[CC][64];
    __shared__ float sB[CC][64];
    __shared__ float red_sum[16][64];
    __shared__ unsigned long long red_pk[16][64];

    const int tid = threadIdx.x;
    const int tx  = tid & 15;
    const int ty  = tid >> 4;
    const int tx4 = tx << 2;
    const int ty4 = ty << 2;
    const int b   = blockIdx.x >> 4;
    const int i0  = (blockIdx.x & 15) << 6;

    const float* Ab = rgb + (size_t)b * CC * LL;
    const float* Bb = ir  + (size_t)b * CC * LL;
    {
        float4 rn = *(const float4*)(rnA + b * LL + i0 + tx4);
#pragma unroll
        for (int r = 0; r < 4; ++r) {
            int c = ty + r * 16;
            float4 v = *(const float4*)(Ab + (size_t)c * LL + i0 + tx4);
            float4 w;
            w.x = v.x * rn.x; w.y = v.y * rn.y; w.z = v.z * rn.z; w.w = v.w * rn.w;
            *(float4*)&sA[c][tx4] = w;
        }
    }
    float rmax[4] = {0.f, 0.f, 0.f, 0.f};
    float rsum[4] = {0.f, 0.f, 0.f, 0.f};
    int   rarg[4] = {0, 0, 0, 0};

    for (int jt = 0; jt < 16; ++jt) {
        const int j0 = jt << 6;
        __syncthreads();
        {
            float4 rn = *(const float4*)(rnB + b * LL + j0 + tx4);
#pragma unroll
            for (int r = 0; r < 4; ++r) {
                int c = ty + r * 16;
                float4 v = *(const float4*)(Bb + (size_t)c * LL + j0 + tx4);
                float4 w;
                w.x = v.x * rn.x; w.y = v.y * rn.y; w.z = v.z * rn.z; w.w = v.w * rn.w;
                *(float4*)&sB[c][tx4] = w;
            }
        }
        __syncthreads();

        float acc[4][4] = {{0.f}};
#pragma unroll 8
        for (int k = 0; k < CC; ++k) {
            const float4 af = *(const float4*)&sA[k][ty4];
            const float4 bf = *(const float4*)&sB[k][tx4];
            const float av[4] = {af.x, af.y, af.z, af.w};
            const float bv[4] = {bf.x, bf.y, bf.z, bf.w};
#pragma unroll
            for (int u = 0; u < 4; ++u)
#pragma unroll
                for (int v = 0; v < 4; ++v)
                    acc[u][v] = fmaf(av[u], bv[v], acc[u][v]);
        }
        float e[4][4];
#pragma unroll
        for (int u = 0; u < 4; ++u)
#pragma unroll
            for (int v = 0; v < 4; ++v)
                e[u][v] = __expf(acc[u][v] * 10.0f);
#pragma unroll
        for (int u = 0; u < 4; ++u) {
#pragma unroll
            for (int v = 0; v < 4; ++v) {
                int j = j0 + tx4 + v;
                float ev = e[u][v];
                if (ev > rmax[u]) { rmax[u] = ev; rarg[u] = j; }
                rsum[u] += ev;
            }
        }
#pragma unroll
        for (int v = 0; v < 4; ++v) {
            float cm = e[0][v]; int ci = 0;
            float cs = e[0][v];
#pragma unroll
            for (int u = 1; u < 4; ++u) {
                float ev = e[u][v];
                if (ev > cm) { cm = ev; ci = u; }
                cs += ev;
            }
            red_sum[ty][tx4 + v] = cs;
            unsigned int inv = ~(unsigned int)(i0 + ty4 + ci);
            red_pk[ty][tx4 + v] =
                ((unsigned long long)__float_as_uint(cm) << 32) | (unsigned long long)inv;
        }
        __syncthreads();
        if (tid < 64) {
            float s = 0.f;
            unsigned long long mm = 0ull;
#pragma unroll
            for (int tt = 0; tt < 16; ++tt) {
                s += red_sum[tt][tid];
                unsigned long long pk = red_pk[tt][tid];
                if (pk > mm) mm = pk;
            }
            atomicAdd(&col_sum[b * LL + j0 + tid], s);
            atomicMax(&col_packed[b * LL + j0 + tid], mm);
        }
    }
    __syncthreads();
#pragma unroll
    for (int u = 0; u < 4; ++u) {
        red_sum[tx][ty4 + u] = rsum[u];
        red_pk[tx][ty4 + u] =
            ((unsigned long long)__float_as_uint(rmax[u]) << 32) |
            (unsigned long long)(unsigned int)(~(unsigned int)rarg[u]);
    }
    __syncthreads();
    if (tid < 64) {
        float s = 0.f;
        unsigned long long mm = 0ull;
#pragma unroll
        for (int tt = 0; tt < 16; ++tt) {
            s += red_sum[tt][tid];
            unsigned long long pk = red_pk[tt][tid];
            if (pk > mm) mm = pk;
        }
        int idx = b * LL + i0 + tid;
        row_sum[idx] = s;
        row_max[idx] = __uint_as_float((unsigned int)(mm >> 32));
        row_arg[idx] = (int)(~(unsigned int)(mm & 0xFFFFFFFFull));
    }
}

__global__ __launch_bounds__(256) void loss_kernel_fb(
        const float* __restrict__ row_max, const float* __restrict__ row_sum,
        const int* __restrict__ row_arg,
        const float* __restrict__ col_sum,
        const unsigned long long* __restrict__ col_packed,
        float* __restrict__ loss_acc) {
    int t = blockIdx.x * 256 + threadIdx.x;
    float acc = 0.f;
#pragma unroll
    for (int it = 0; it < 4; ++it) {
        int p = t + it * 16384;
        if (p < NB * LL) {
            float m2 = row_max[p], s2 = row_sum[p];
            int b = p >> 10;
            int qq = (b << 10) + row_arg[p];
            unsigned long long pk = col_packed[qq];
            float m1 = __uint_as_float((unsigned int)(pk >> 32));
            float s1 = col_sum[p];                    // position-indexed (fixed)
            acc += logf((m2 / (s2 + EPS)) * (m1 / (s1 + EPS)));
        } else {
            int p2 = p - NB * LL;
            unsigned long long pk = col_packed[p2];
            float m1 = __uint_as_float((unsigned int)(pk >> 32));
            float s1 = col_sum[p2];
            int b = p2 >> 10;
            int qq = (b << 10) + (int)(~(unsigned int)(pk & 0xFFFFFFFFull));
            float m2 = row_max[qq];
            float s2 = row_sum[p2];                   // position-indexed (fixed)
            acc += logf((m1 / (s1 + EPS)) * (m2 / (s2 + EPS)));
        }
    }
#pragma unroll
    for (int off = 32; off > 0; off >>= 1) acc += __shfl_down(acc, off, 64);
    __shared__ float wsum[4];
    int lane = threadIdx.x & 63, w = threadIdx.x >> 6;
    if (lane == 0) wsum[w] = acc;
    __syncthreads();
    if (threadIdx.x == 0)
        atomicAdd(loss_acc, wsum[0] + wsum[1] + wsum[2] + wsum[3]);
}

// ============================================================================
extern "C" void kernel_launch(void* const* d_in, const int* in_sizes, int n_in,
                              void* d_out, int out_size, void* d_ws, size_t ws_size,
                              hipStream_t stream) {
    const float* rgb = (const float*)d_in[0];
    const float* ir  = (const float*)d_in[1];
    char* wsb = (char*)d_ws;

    if (ws_size >= 8912900) {
        __bf16*   At      = (__bf16*)(wsb);
        __bf16*   Bt      = (__bf16*)(wsb + 4194304);
        float*    row_sum = (float*)(wsb + 8388608);
        float*    col_sum = (float*)(wsb + 8519680);
        unsigned* row_pk  = (unsigned*)(wsb + 8650752);
        unsigned* col_pk  = (unsigned*)(wsb + 8781824);
        float*    loss    = (float*)(wsb + 8912896);

        hipMemsetAsync(wsb + 8388608, 0, 524292, stream);
        transpose_norm_kernel<<<1024, 256, 0, stream>>>(rgb, ir, At, Bt);
        gemm_stats_kernel<<<2048, 256, 0, stream>>>(At, Bt, row_sum, row_pk,
                                                    col_sum, col_pk);
        loss_kernel2<<<64, 256, 0, stream>>>(row_sum, row_pk, col_sum, col_pk, loss);
        finalize_kernel<<<1, 1, 0, stream>>>(loss, (float*)d_out);
    } else {
        float* ws = (float*)d_ws;
        float* rnA     = ws;
        float* rnB     = ws + 32768;
        float* row_max = ws + 65536;
        float* row_sum = ws + 98304;
        int*   row_arg = (int*)(ws + 131072);
        float* col_sum = ws + 163840;
        unsigned long long* col_packed = (unsigned long long*)(ws + 196608);
        float* loss_acc = ws + 262144;

        hipMemsetAsync(ws + 163840, 0, (size_t)(32768 + 65536 + 1) * sizeof(float), stream);
        norms_kernel_fb<<<128, 256, 0, stream>>>(rgb, ir, rnA, rnB);
        fused_kernel_fb<<<NB * 16, 256, 0, stream>>>(rgb, ir, rnA, rnB,
                                                     row_max, row_sum, row_arg,
                                                     col_sum, col_packed);
        loss_kernel_fb<<<64, 256, 0, stream>>>(row_max, row_sum, row_arg,
                                               col_sum, col_packed, loss_acc);
        finalize_kernel<<<1, 1, 0, stream>>>(loss_acc, (float*)d_out);
    }
}